// Round 19
// baseline (64.886 us; speedup 1.0000x reference)
//
#include <hip/hip_runtime.h>
#include <stdint.h>

#define UNITS 64
#define UU 4096          // UNITS*UNITS
#define NG 50
#define NSLOT 51         // 50 gaussians + 1 bias slot
#define GAMMA_C 10.0f
#define STEP_C (30.0f / 49.0f)
#define NWIN 4           // gaussian window width (centers lo..lo+3)
#define NBKT 47          // lo in [0, 46]
#define NCHK 64          // contiguous edge chunks (scatter blocks)

typedef __attribute__((ext_vector_type(8))) short bf16x8;
typedef __attribute__((ext_vector_type(4))) float f32x4;

union bfr_t { bf16x8 v; uint32_t u[4]; };

__device__ __forceinline__ uint16_t f2bf(float x) {
  uint32_t u = __float_as_uint(x);
  u += 0x7fffu + ((u >> 16) & 1u);           // RNE to bf16
  return (uint16_t)(u >> 16);
}
__device__ __forceinline__ uint32_t pk_bf16(float lo, float hi) {
  uint32_t r;
  asm("v_cvt_pk_bf16_f32 %0, %1, %2" : "=v"(r) : "v"(lo), "v"(hi));
  return r;
}
__device__ __forceinline__ int lo_of(float d) {
  int lo = (int)floorf(d * (1.0f / STEP_C)) - 1;
  return min(max(lo, 0), NG - NWIN);
}

// ===== k_at: ALL prep in one launch, grid (16, 63) =====
//  y<51   : T5 (R10/R13-verified)
//  y 51-58: zero msg (128 blocks)
//  y 59-62: self-sufficient deterministic scatter (64 blocks): each block
//           scans dist fully (htot + hpre), derives bases, places its chunk.
//           Block 0 also writes meta (bucket totals) + fills pad slots.
__global__ void __launch_bounds__(256) k_at(
    const float* __restrict__ W1, const float* __restrict__ b1,
    const float* __restrict__ W2, const float* __restrict__ b2,
    const float* __restrict__ Wt, const float* __restrict__ dist,
    uint16_t* __restrict__ T5B, float* __restrict__ msg,
    int* __restrict__ meta, int* __restrict__ eidx,
    int n_out, int E) {
  int g = blockIdx.y, bx = blockIdx.x;
  if (g >= NSLOT) {
    if (g < NSLOT + 8) {                       // zero msg
      int n4 = n_out >> 2;
      float4 z = {0.f, 0.f, 0.f, 0.f};
      for (int t = ((g - NSLOT) * 16 + bx) * 256 + threadIdx.x; t < n4; t += 128 * 256)
        reinterpret_cast<float4*>(msg)[t] = z;
      return;
    }
    // scatter: block sb owns chunk [e0,e1); offsets fully deterministic
    __shared__ int htot[NBKT], hpre[NBKT], hbase[NBKT], hcur[NBKT];
    int sb = (g - (NSLOT + 8)) * 16 + bx;      // 0..63
    int per = (E + NCHK - 1) / NCHK;
    int e0 = sb * per, e1 = min(e0 + per, E);
    for (int i = threadIdx.x; i < NBKT; i += 256) {
      htot[i] = 0; hpre[i] = 0; hcur[i] = 0;
    }
    __syncthreads();
    for (int e = threadIdx.x; e < E; e += 256) {   // full scan (coalesced)
      int b = lo_of(dist[e]);
      atomicAdd(&htot[b], 1);                  // LDS atomic
      if (e < e0) atomicAdd(&hpre[b], 1);
    }
    __syncthreads();
    if (threadIdx.x < 64) {                    // wave 0: bucket bases
      int lane = threadIdx.x;
      int tot = (lane < NBKT) ? htot[lane] : 0;
      int cap = (tot + 15) & ~15;
      int inc = cap;
      #pragma unroll
      for (int s = 1; s < 64; s <<= 1) {
        int t = __shfl_up(inc, s, 64);
        if (lane >= s) inc += t;
      }
      if (lane < NBKT) hbase[lane] = (inc - cap) + hpre[lane];
    }
    __syncthreads();
    for (int e = e0 + threadIdx.x; e < e1; e += 256) {
      int b = lo_of(dist[e]);
      int p = hbase[b] + atomicAdd(&hcur[b], 1);   // LDS cursor
      eidx[p] = e;
    }
    if (sb == 0) {                             // block 0: meta + pad fill
      if (threadIdx.x < 64)
        meta[threadIdx.x] = (threadIdx.x < NBKT) ? htot[threadIdx.x] : 0;
      if (threadIdx.x < NBKT) {
        int b0 = hbase[threadIdx.x];           // hpre==0 for sb==0 -> pure base
        int t = htot[threadIdx.x];
        int c = (t + 15) & ~15;
        for (int i = b0 + t; i < b0 + c; ++i) eidx[i] = -1;
      }
    }
    return;
  }
  __shared__ float Aloc[256];
  __shared__ float WtL[64 * 65];               // padded: row stride 65
  const int t = threadIdx.x;
  const int ij = bx * 256 + t;

  #pragma unroll
  for (int q = 0; q < 4; ++q) {
    int idx = q * 256 + t;
    float4 v = reinterpret_cast<const float4*>(Wt)[idx];
    int mm = idx >> 4, jj = (idx & 15) * 4;
    float* dst = &WtL[mm * 65 + jj];
    dst[0] = v.x; dst[1] = v.y; dst[2] = v.z; dst[3] = v.w;
  }
  {
    float acc = 0.f;
    if (g < NG) {
      const float* w1r = W1 + g * UNITS;
      #pragma unroll 8
      for (int k = 0; k < UNITS; ++k) acc = fmaf(w1r[k], W2[k * UU + ij], acc);
    } else {
      #pragma unroll 8
      for (int k = 0; k < UNITS; ++k) acc = fmaf(b1[k], W2[k * UU + ij], acc);
      acc += b2[ij];
    }
    Aloc[t] = acc;
  }
  __syncthreads();

  const int i_local = t >> 6, m = t & 63;
  const float* ar = &Aloc[i_local * 64];
  const float* wr = &WtL[m * 65];
  float acc = 0.f;
  #pragma unroll 8
  for (int j = 0; j < UNITS; ++j) acc = fmaf(ar[j], wr[j], acc);
  const int gi = bx * 4 + i_local;
  T5B[(((g << 3) + (m >> 3)) << 9) + (gi << 3) + (m & 7)] = f2bf(acc);
}

// ===== k_em: 2 tiles/wave, meta-driven bucket map, LDS-transposed
//       coalesced atomics (R16/R18-verified back-end) =====
__global__ void __launch_bounds__(256) k_em(
    const float* __restrict__ nf, const int* __restrict__ ei,
    const float* __restrict__ dist, const uint16_t* __restrict__ T5B,
    const int* __restrict__ eidx, const int* __restrict__ meta,
    float* __restrict__ msg, int E) {
  __shared__ float tile[4][16 * 64];           // 4 KB per wave (reused by both tiles)
  int w = threadIdx.x >> 6, l = threadIdx.x & 63;
  int lr = l & 15, lg = l >> 4;

  // tile-caps prefix scan over bucket totals (1 load/lane)
  int tot = (l < NBKT) ? meta[l] : 0;
  int tcap = (tot + 15) >> 4;                  // tiles in bucket l
  int p = tcap;
  #pragma unroll
  for (int s = 1; s < 64; s <<= 1) {
    int tt = __shfl_up(p, s, 64);
    if (l >= s) p += tt;
  }
  int total = __shfl(p, 63);

  int tA = (blockIdx.x * 4 + w) * 2, tB = tA + 1;
  if (tA >= total) return;                     // wave-uniform exit
  bool actB = (tB < total);

  uint64_t mA = __ballot(tA < p);
  int bA = __ffsll((unsigned long long)mA) - 1;
  int bB = bA;
  if (actB) {
    uint64_t mB = __ballot(tB < p);
    bB = __ffsll((unsigned long long)mB) - 1;
  }

  // front-end: issue both tiles' gather chains (eidx -> ei/dist -> nf)
  int eA = eidx[tA * 16 + lr];
  int eB = actB ? eidx[tB * 16 + lr] : -1;
  bool vA = (eA >= 0), vB = (eB >= 0);
  int srcA = vA ? ei[eA] : 0, dstA = vA ? ei[E + eA] : -1;
  int srcB = vB ? ei[eB] : 0, dstB = vB ? ei[E + eB] : -1;
  float dA = vA ? dist[eA] : 3.0e30f;
  float dB = vB ? dist[eB] : 3.0e30f;

  bfr_t afrA[2], afrB[2];
  {
    const float4* abA = reinterpret_cast<const float4*>(nf + srcA * UNITS) + lg * 2;
    const float4* abB = reinterpret_cast<const float4*>(nf + srcB * UNITS) + lg * 2;
    #pragma unroll
    for (int kk = 0; kk < 2; ++kk) {
      float4 a0 = abA[kk * 8], a1 = abA[kk * 8 + 1];
      float4 b0 = abB[kk * 8], b1 = abB[kk * 8 + 1];
      afrA[kk].u[0] = pk_bf16(a0.x, a0.y); afrA[kk].u[1] = pk_bf16(a0.z, a0.w);
      afrA[kk].u[2] = pk_bf16(a1.x, a1.y); afrA[kk].u[3] = pk_bf16(a1.z, a1.w);
      afrB[kk].u[0] = pk_bf16(b0.x, b0.y); afrB[kk].u[1] = pk_bf16(b0.z, b0.w);
      afrB[kk].u[2] = pk_bf16(b1.x, b1.y); afrB[kk].u[3] = pk_bf16(b1.z, b1.w);
    }
  }

  float* tw = tile[w];
  // back-end (R16-verified): df -> MFMA -> LDS transpose -> coalesced atomics
  auto run_tile = [&](int b, float d, bool valid, int dst, bfr_t* afr) {
    float df[5];
    #pragma unroll
    for (int s = 0; s < NWIN; ++s) {
      float tt = d - (float)(b + s) * STEP_C;
      df[s] = __expf(-GAMMA_C * tt * tt);
    }
    df[NWIN] = valid ? 1.f : 0.f;              // bias slot

    f32x4 run[4] = {};
    #pragma unroll
    for (int s = 0; s < 5; ++s) {
      int g = (s < NWIN) ? (b + s) : NG;
      const char* bb = (const char*)T5B + (g << 13) + (lg << 10) + (lr << 6);
      f32x4 acc[4] = {};
      #pragma unroll
      for (int kk = 0; kk < 2; ++kk)
        #pragma unroll
        for (int nt = 0; nt < 4; ++nt) {
          bf16x8 bf = *reinterpret_cast<const bf16x8*>(bb + (kk << 12) + (nt << 4));
          acc[nt] = __builtin_amdgcn_mfma_f32_16x16x32_bf16(afr[kk].v, bf, acc[nt], 0, 0, 0);
        }
      float dfq[4];
      #pragma unroll
      for (int q = 0; q < 4; ++q) dfq[q] = __shfl(df[s], lg * 4 + q, 64);
      #pragma unroll
      for (int nt = 0; nt < 4; ++nt)
        #pragma unroll
        for (int q = 0; q < 4; ++q)
          run[nt][q] = fmaf(dfq[q], acc[nt][q], run[nt][q]);
    }

    #pragma unroll
    for (int q = 0; q < 4; ++q) {
      float4 v4 = {run[0][q], run[1][q], run[2][q], run[3][q]};
      *reinterpret_cast<float4*>(&tw[(lg * 4 + q) * 64 + 4 * lr]) = v4;
    }
    asm volatile("" ::: "memory");             // same-wave DS ops are in-order

    #pragma unroll
    for (int r = 0; r < 16; ++r) {
      int dr = __shfl(dst, r, 64);             // lane r holds edge r's dst
      if (dr < 0) continue;                    // wave-uniform skip for dummy rows
      atomicAdd(&msg[dr * UNITS + l], tw[r * 64 + l]);
    }
  };

  run_tile(bA, dA, vA, dstA, afrA);
  if (actB) run_tile(bB, dB, vB, dstB, afrB);
}

// out = softplus(msg) - ln(2)
__global__ void k_final(const float* __restrict__ msg, float* __restrict__ out,
                        int n_out) {
  int i4 = blockIdx.x * 256 + threadIdx.x;
  if (i4 >= (n_out >> 2)) return;
  float4 a = reinterpret_cast<const float4*>(msg)[i4];
  float4 r;
  r.x = ((a.x > 0.f) ? (a.x + log1pf(__expf(-a.x))) : log1pf(__expf(a.x))) - 0.69314718056f;
  r.y = ((a.y > 0.f) ? (a.y + log1pf(__expf(-a.y))) : log1pf(__expf(a.y))) - 0.69314718056f;
  r.z = ((a.z > 0.f) ? (a.z + log1pf(__expf(-a.z))) : log1pf(__expf(a.z))) - 0.69314718056f;
  r.w = ((a.w > 0.f) ? (a.w + log1pf(__expf(-a.w))) : log1pf(__expf(a.w))) - 0.69314718056f;
  reinterpret_cast<float4*>(out)[i4] = r;
}

extern "C" void kernel_launch(void* const* d_in, const int* in_sizes, int n_in,
                              void* d_out, int out_size, void* d_ws, size_t ws_size,
                              hipStream_t stream) {
  const float* nf   = (const float*)d_in[0];
  const int*   ei   = (const int*)d_in[1];
  const float* dist = (const float*)d_in[2];
  const float* W1   = (const float*)d_in[3];
  const float* b1   = (const float*)d_in[4];
  const float* W2   = (const float*)d_in[5];
  const float* b2   = (const float*)d_in[6];
  const float* Wt   = (const float*)d_in[7];
  float* out = (float*)d_out;

  int E = in_sizes[2];               // 50000
  int n_out = out_size;              // N_NODES * UNITS

  int mt = E / 16 + NBKT + 1;        // max 16-edge tiles

  // workspace layout (no memset: meta/eidx fully rewritten each replay)
  char* ws = (char*)d_ws;
  size_t off_msg  = 417792;                          // T5B: 51*4096*2
  size_t off_meta = off_msg + (size_t)n_out * 4;     // msg
  size_t off_eidx = off_meta + 64 * 4;               // meta: 64 ints

  uint16_t* T5B  = (uint16_t*)ws;
  float*    msg  = (float*)(ws + off_msg);
  int*      meta = (int*)(ws + off_meta);
  int*      eidx = (int*)(ws + off_eidx);

  k_at  <<<dim3(16, NSLOT + 12), 256, 0, stream>>>(W1, b1, W2, b2, Wt, dist,
                                                   T5B, msg, meta, eidx, n_out, E);
  k_em  <<<(mt + 7) / 8, 256, 0, stream>>>(nf, ei, dist, T5B, eidx, meta, msg, E);
  k_final<<<((n_out >> 2) + 255) / 256, 256, 0, stream>>>(msg, out, n_out);
}

// Round 20
// 42.950 us; speedup vs baseline: 1.5107x; 1.5107x over previous
//
#include <hip/hip_runtime.h>
#include <stdint.h>

#define UNITS 64
#define UU 4096          // UNITS*UNITS
#define NG 50
#define NSLOT 51         // 50 gaussians + 1 bias slot
#define GAMMA_C 10.0f
#define STEP_C (30.0f / 49.0f)
#define NWIN 4           // gaussian window width (centers lo..lo+3)
#define NBKT 47          // lo in [0, 46]
#define NCHK 64          // contiguous edge chunks (hist/scatter blocks)

typedef __attribute__((ext_vector_type(8))) short bf16x8;
typedef __attribute__((ext_vector_type(4))) float f32x4;

union bfr_t { bf16x8 v; uint32_t u[4]; };

__device__ __forceinline__ uint16_t f2bf(float x) {
  uint32_t u = __float_as_uint(x);
  u += 0x7fffu + ((u >> 16) & 1u);           // RNE to bf16
  return (uint16_t)(u >> 16);
}
__device__ __forceinline__ uint32_t pk_bf16(float lo, float hi) {
  uint32_t r;
  asm("v_cvt_pk_bf16_f32 %0, %1, %2" : "=v"(r) : "v"(lo), "v"(hi));
  return r;
}
__device__ __forceinline__ int lo_of(float d) {
  int lo = (int)floorf(d * (1.0f / STEP_C)) - 1;
  return min(max(lo, 0), NG - NWIN);
}

// ===== k_hist: contiguous chunks, per-block hist via PLAIN stores (no memset,
//       no global atomics) + eidx -1 prefill =====
__global__ void __launch_bounds__(256) k_hist(const float* __restrict__ dist,
                                              int* __restrict__ binsB,
                                              int* __restrict__ eidx, int E, int ne) {
  __shared__ int hloc[NBKT];
  for (int i = threadIdx.x; i < NBKT; i += 256) hloc[i] = 0;
  __syncthreads();
  int per = (E + NCHK - 1) / NCHK;
  int e0 = blockIdx.x * per, e1 = min(e0 + per, E);
  for (int e = e0 + threadIdx.x; e < e1; e += 256)
    atomicAdd(&hloc[lo_of(dist[e])], 1);       // LDS atomic
  __syncthreads();
  for (int i = threadIdx.x; i < 64; i += 256)
    binsB[blockIdx.x * 64 + i] = (i < NBKT) ? hloc[i] : 0;   // plain store
  for (int i = blockIdx.x * 256 + threadIdx.x; i < ne; i += NCHK * 256) eidx[i] = -1;
}

// ===== k_at: fused precompute, grid (16, 63) =====
//  y<51   : T5 (R10/R13-verified)
//  y 51-58: zero msg (128 blocks)
//  y 59-62: DETERMINISTIC bucket scatter (64 blocks = same chunks as k_hist)
__global__ void __launch_bounds__(256) k_at(
    const float* __restrict__ W1, const float* __restrict__ b1,
    const float* __restrict__ W2, const float* __restrict__ b2,
    const float* __restrict__ Wt, const float* __restrict__ dist,
    uint16_t* __restrict__ T5B, float* __restrict__ msg,
    const int* __restrict__ binsB, int* __restrict__ eidx,
    int n_out, int E) {
  int g = blockIdx.y, bx = blockIdx.x;
  if (g >= NSLOT) {
    if (g < NSLOT + 8) {                       // zero msg
      int n4 = n_out >> 2;
      float4 z = {0.f, 0.f, 0.f, 0.f};
      for (int t = ((g - NSLOT) * 16 + bx) * 256 + threadIdx.x; t < n4; t += 128 * 256)
        reinterpret_cast<float4*>(msg)[t] = z;
      return;
    }
    // scatter: block sb owns chunk [e0,e1); offsets fully deterministic
    __shared__ int hbase[NBKT], hcur[NBKT];
    int sb = (g - (NSLOT + 8)) * 16 + bx;      // 0..63
    int per = (E + NCHK - 1) / NCHK;
    int e0 = sb * per, e1 = min(e0 + per, E);
    if (threadIdx.x < 64) {                    // wave 0: bases
      int lane = threadIdx.x;
      int tot = 0, pre = 0;
      for (int j = 0; j < NCHK; ++j) {
        int v = binsB[j * 64 + lane];          // coalesced, L2-hot
        tot += v;
        if (j < sb) pre += v;
      }
      int cap = (tot + 15) & ~15;              // 0 for lane>=NBKT (tot==0)
      int inc = cap;
      #pragma unroll
      for (int s = 1; s < 64; s <<= 1) {
        int t = __shfl_up(inc, s, 64);
        if (lane >= s) inc += t;
      }
      if (lane < NBKT) { hbase[lane] = (inc - cap) + pre; hcur[lane] = 0; }
    }
    __syncthreads();
    for (int e = e0 + threadIdx.x; e < e1; e += 256) {
      int b = lo_of(dist[e]);
      int p = hbase[b] + atomicAdd(&hcur[b], 1);   // LDS cursor
      eidx[p] = e;
    }
    return;
  }
  __shared__ float Aloc[256];
  __shared__ float WtL[64 * 65];               // padded: row stride 65
  const int t = threadIdx.x;
  const int ij = bx * 256 + t;

  #pragma unroll
  for (int q = 0; q < 4; ++q) {
    int idx = q * 256 + t;
    float4 v = reinterpret_cast<const float4*>(Wt)[idx];
    int mm = idx >> 4, jj = (idx & 15) * 4;
    float* dst = &WtL[mm * 65 + jj];
    dst[0] = v.x; dst[1] = v.y; dst[2] = v.z; dst[3] = v.w;
  }
  {
    float acc = 0.f;
    if (g < NG) {
      const float* w1r = W1 + g * UNITS;
      #pragma unroll 8
      for (int k = 0; k < UNITS; ++k) acc = fmaf(w1r[k], W2[k * UU + ij], acc);
    } else {
      #pragma unroll 8
      for (int k = 0; k < UNITS; ++k) acc = fmaf(b1[k], W2[k * UU + ij], acc);
      acc += b2[ij];
    }
    Aloc[t] = acc;
  }
  __syncthreads();

  const int i_local = t >> 6, m = t & 63;
  const float* ar = &Aloc[i_local * 64];
  const float* wr = &WtL[m * 65];
  float acc = 0.f;
  #pragma unroll 8
  for (int j = 0; j < UNITS; ++j) acc = fmaf(ar[j], wr[j], acc);
  const int gi = bx * 4 + i_local;
  T5B[(((g << 3) + (m >> 3)) << 9) + (gi << 3) + (m & 7)] = f2bf(acc);
}

// ===== k_em: 2 tiles/wave (gathers overlapped), in-wave bucket map,
//       LDS-transposed coalesced atomics (R12/R13-verified back-end) =====
__global__ void __launch_bounds__(256) k_em(
    const float* __restrict__ nf, const int* __restrict__ ei,
    const float* __restrict__ dist, const uint16_t* __restrict__ T5B,
    const int* __restrict__ eidx, const int* __restrict__ binsB,
    float* __restrict__ msg, int E) {
  __shared__ float tile[4][16 * 64];           // 4 KB per wave (reused by both tiles)
  int w = threadIdx.x >> 6, l = threadIdx.x & 63;
  int lr = l & 15, lg = l >> 4;

  // bucket totals (sum of per-chunk hists), then tile-caps prefix scan
  int tot = 0;
  #pragma unroll 8
  for (int j = 0; j < NCHK; ++j) tot += binsB[j * 64 + l];
  int tcap = (tot + 15) >> 4;                  // tiles in bucket l (0 for l>=NBKT)
  int p = tcap;
  #pragma unroll
  for (int s = 1; s < 64; s <<= 1) {
    int tt = __shfl_up(p, s, 64);
    if (l >= s) p += tt;
  }
  int total = __shfl(p, 63);

  int tA = (blockIdx.x * 4 + w) * 2, tB = tA + 1;
  if (tA >= total) return;                     // wave-uniform exit
  bool actB = (tB < total);

  uint64_t mA = __ballot(tA < p);
  int bA = __ffsll((unsigned long long)mA) - 1;
  int bB = bA;
  if (actB) {
    uint64_t mB = __ballot(tB < p);
    bB = __ffsll((unsigned long long)mB) - 1;
  }

  // front-end: issue both tiles' gather chains (eidx -> ei/dist -> nf)
  int eA = eidx[tA * 16 + lr];
  int eB = actB ? eidx[tB * 16 + lr] : -1;
  bool vA = (eA >= 0), vB = (eB >= 0);
  int srcA = vA ? ei[eA] : 0, dstA = vA ? ei[E + eA] : -1;
  int srcB = vB ? ei[eB] : 0, dstB = vB ? ei[E + eB] : -1;
  float dA = vA ? dist[eA] : 3.0e30f;
  float dB = vB ? dist[eB] : 3.0e30f;

  bfr_t afrA[2], afrB[2];
  {
    const float4* abA = reinterpret_cast<const float4*>(nf + srcA * UNITS) + lg * 2;
    const float4* abB = reinterpret_cast<const float4*>(nf + srcB * UNITS) + lg * 2;
    #pragma unroll
    for (int kk = 0; kk < 2; ++kk) {
      float4 a0 = abA[kk * 8], a1 = abA[kk * 8 + 1];
      float4 b0 = abB[kk * 8], b1 = abB[kk * 8 + 1];
      afrA[kk].u[0] = pk_bf16(a0.x, a0.y); afrA[kk].u[1] = pk_bf16(a0.z, a0.w);
      afrA[kk].u[2] = pk_bf16(a1.x, a1.y); afrA[kk].u[3] = pk_bf16(a1.z, a1.w);
      afrB[kk].u[0] = pk_bf16(b0.x, b0.y); afrB[kk].u[1] = pk_bf16(b0.z, b0.w);
      afrB[kk].u[2] = pk_bf16(b1.x, b1.y); afrB[kk].u[3] = pk_bf16(b1.z, b1.w);
    }
  }

  float* tw = tile[w];
  // back-end (R16-verified): df -> MFMA -> LDS transpose -> coalesced atomics
  auto run_tile = [&](int b, float d, bool valid, int dst, bfr_t* afr) {
    float df[5];
    #pragma unroll
    for (int s = 0; s < NWIN; ++s) {
      float tt = d - (float)(b + s) * STEP_C;
      df[s] = __expf(-GAMMA_C * tt * tt);
    }
    df[NWIN] = valid ? 1.f : 0.f;              // bias slot

    f32x4 run[4] = {};
    #pragma unroll
    for (int s = 0; s < 5; ++s) {
      int g = (s < NWIN) ? (b + s) : NG;
      const char* bb = (const char*)T5B + (g << 13) + (lg << 10) + (lr << 6);
      f32x4 acc[4] = {};
      #pragma unroll
      for (int kk = 0; kk < 2; ++kk)
        #pragma unroll
        for (int nt = 0; nt < 4; ++nt) {
          bf16x8 bf = *reinterpret_cast<const bf16x8*>(bb + (kk << 12) + (nt << 4));
          acc[nt] = __builtin_amdgcn_mfma_f32_16x16x32_bf16(afr[kk].v, bf, acc[nt], 0, 0, 0);
        }
      float dfq[4];
      #pragma unroll
      for (int q = 0; q < 4; ++q) dfq[q] = __shfl(df[s], lg * 4 + q, 64);
      #pragma unroll
      for (int nt = 0; nt < 4; ++nt)
        #pragma unroll
        for (int q = 0; q < 4; ++q)
          run[nt][q] = fmaf(dfq[q], acc[nt][q], run[nt][q]);
    }

    #pragma unroll
    for (int q = 0; q < 4; ++q) {
      float4 v4 = {run[0][q], run[1][q], run[2][q], run[3][q]};
      *reinterpret_cast<float4*>(&tw[(lg * 4 + q) * 64 + 4 * lr]) = v4;
    }
    asm volatile("" ::: "memory");             // same-wave DS ops are in-order

    #pragma unroll
    for (int r = 0; r < 16; ++r) {
      int dr = __shfl(dst, r, 64);             // lane r holds edge r's dst
      if (dr < 0) continue;                    // wave-uniform skip for dummy rows
      atomicAdd(&msg[dr * UNITS + l], tw[r * 64 + l]);
    }
  };

  run_tile(bA, dA, vA, dstA, afrA);
  if (actB) run_tile(bB, dB, vB, dstB, afrB);
}

// out = softplus(msg) - ln(2)
__global__ void k_final(const float* __restrict__ msg, float* __restrict__ out,
                        int n_out) {
  int i4 = blockIdx.x * 256 + threadIdx.x;
  if (i4 >= (n_out >> 2)) return;
  float4 a = reinterpret_cast<const float4*>(msg)[i4];
  float4 r;
  r.x = ((a.x > 0.f) ? (a.x + log1pf(__expf(-a.x))) : log1pf(__expf(a.x))) - 0.69314718056f;
  r.y = ((a.y > 0.f) ? (a.y + log1pf(__expf(-a.y))) : log1pf(__expf(a.y))) - 0.69314718056f;
  r.z = ((a.z > 0.f) ? (a.z + log1pf(__expf(-a.z))) : log1pf(__expf(a.z))) - 0.69314718056f;
  r.w = ((a.w > 0.f) ? (a.w + log1pf(__expf(-a.w))) : log1pf(__expf(a.w))) - 0.69314718056f;
  reinterpret_cast<float4*>(out)[i4] = r;
}

extern "C" void kernel_launch(void* const* d_in, const int* in_sizes, int n_in,
                              void* d_out, int out_size, void* d_ws, size_t ws_size,
                              hipStream_t stream) {
  const float* nf   = (const float*)d_in[0];
  const int*   ei   = (const int*)d_in[1];
  const float* dist = (const float*)d_in[2];
  const float* W1   = (const float*)d_in[3];
  const float* b1   = (const float*)d_in[4];
  const float* W2   = (const float*)d_in[5];
  const float* b2   = (const float*)d_in[6];
  const float* Wt   = (const float*)d_in[7];
  float* out = (float*)d_out;

  int E = in_sizes[2];               // 50000
  int n_out = out_size;              // N_NODES * UNITS

  int mt = E / 16 + NBKT + 1;        // max 16-edge tiles
  int ne = mt * 16;                  // eidx entries

  // workspace layout (no memset needed: binsB fully overwritten each replay)
  char* ws = (char*)d_ws;
  size_t off_msg   = 417792;                         // T5B: 51*4096*2
  size_t off_binsB = off_msg + (size_t)n_out * 4;    // msg
  size_t off_eidx  = off_binsB + NCHK * 64 * 4;      // binsB: 64 chunks x 64 ints

  uint16_t* T5B   = (uint16_t*)ws;
  float*    msg   = (float*)(ws + off_msg);
  int*      binsB = (int*)(ws + off_binsB);
  int*      eidx  = (int*)(ws + off_eidx);

  k_hist<<<NCHK, 256, 0, stream>>>(dist, binsB, eidx, E, ne);
  k_at  <<<dim3(16, NSLOT + 12), 256, 0, stream>>>(W1, b1, W2, b2, Wt, dist,
                                                   T5B, msg, binsB, eidx, n_out, E);
  k_em  <<<(mt + 7) / 8, 256, 0, stream>>>(nf, ei, dist, T5B, eidx, binsB, msg, E);
  k_final<<<((n_out >> 2) + 255) / 256, 256, 0, stream>>>(msg, out, n_out);
}